// Round 2
// baseline (1191.787 us; speedup 1.0000x reference)
//
#include <hip/hip_runtime.h>
#include <math.h>

#define NPTS 1024
#define NBATCH 8
#define KNN 20
#define EPSBN 1e-5f
#define NSLOPE 0.2f

__device__ __forceinline__ float lrelu_f(float x){ return x >= 0.f ? x : NSLOPE*x; }

// ---------------- xx[b,n] = sum_c X[b,c,n]^2 (f64) ----------------
__global__ void xx_kernel_f64(const float* __restrict__ X, long bstride, int coff, int C,
                              double* __restrict__ XXd){
  int g = blockIdx.x*blockDim.x + threadIdx.x;
  int n = g & (NPTS-1);
  int b = g >> 10;
  const float* p = X + (size_t)b*bstride + (size_t)coff*NPTS + n;
  double s = 0.0;
  for (int c = 0; c < C; ++c){ double v = (double)p[(size_t)c*NPTS]; s += v*v; }
  XXd[g] = s;
}

// ---------------- pd[b,n,m] = 2*dot(x_n,x_m) - xx[n] - xx[m]  (f64 accumulate) ----------------
__global__ void pd_gemm_f64(const float* __restrict__ X, long bstride, int coff, int C,
                            const double* __restrict__ XXd, double* __restrict__ PDd){
  __shared__ double As[16][64];
  __shared__ double Bs[16][64];
  int b = blockIdx.z;
  int r0 = blockIdx.y * 64;       // pd row tile (n)
  int q0 = blockIdx.x * 64;       // pd col tile (m)
  int t = threadIdx.x;
  int lr = t >> 4;
  int lc = (t & 15) << 2;
  const float* Xb = X + (size_t)b*bstride + (size_t)coff*NPTS;
  const double* xxb = XXd + b*NPTS;
  double acc[4][4] = {};
  for (int k0 = 0; k0 < C; k0 += 16){
    float4 av = make_float4(0,0,0,0);
    float4 bv = make_float4(0,0,0,0);
    if (k0 + lr < C){
      const float* rp = Xb + (size_t)(k0+lr)*NPTS;
      av = *(const float4*)(rp + r0 + lc);
      bv = *(const float4*)(rp + q0 + lc);
    }
    As[lr][lc+0] = (double)av.x; As[lr][lc+1] = (double)av.y;
    As[lr][lc+2] = (double)av.z; As[lr][lc+3] = (double)av.w;
    Bs[lr][lc+0] = (double)bv.x; Bs[lr][lc+1] = (double)bv.y;
    Bs[lr][lc+2] = (double)bv.z; Bs[lr][lc+3] = (double)bv.w;
    __syncthreads();
    int tr = (t >> 4) << 2;
    int tc = (t & 15) << 2;
    #pragma unroll
    for (int kk = 0; kk < 16; ++kk){
      double a0 = As[kk][tr+0], a1 = As[kk][tr+1], a2 = As[kk][tr+2], a3 = As[kk][tr+3];
      double b0 = Bs[kk][tc+0], b1 = Bs[kk][tc+1], b2 = Bs[kk][tc+2], b3 = Bs[kk][tc+3];
      acc[0][0] += a0*b0; acc[0][1] += a0*b1; acc[0][2] += a0*b2; acc[0][3] += a0*b3;
      acc[1][0] += a1*b0; acc[1][1] += a1*b1; acc[1][2] += a1*b2; acc[1][3] += a1*b3;
      acc[2][0] += a2*b0; acc[2][1] += a2*b1; acc[2][2] += a2*b2; acc[2][3] += a2*b3;
      acc[3][0] += a3*b0; acc[3][1] += a3*b1; acc[3][2] += a3*b2; acc[3][3] += a3*b3;
    }
    __syncthreads();
  }
  int tr = (t >> 4) << 2;
  int tc = (t & 15) << 2;
  double x0 = xxb[q0+tc+0], x1 = xxb[q0+tc+1], x2 = xxb[q0+tc+2], x3 = xxb[q0+tc+3];
  #pragma unroll
  for (int i = 0; i < 4; ++i){
    int r = r0 + tr + i;
    double xr = xxb[r];
    double* op = PDd + ((size_t)b*NPTS + r)*NPTS + q0 + tc;
    op[0] = 2.0*acc[i][0] - xr - x0;
    op[1] = 2.0*acc[i][1] - xr - x1;
    op[2] = 2.0*acc[i][2] - xr - x2;
    op[3] = 2.0*acc[i][3] - xr - x3;
  }
}

// ---------------- top-20 per row, f64 (value desc, index asc on ties) ----------------
__global__ void topk_kernel(const double* __restrict__ PDd, int* __restrict__ IDX){
  __shared__ double vals[NPTS];
  __shared__ double rv[256];
  __shared__ int   ri[256];
  int row = blockIdx.x;   // b*NPTS + n
  int t = threadIdx.x;
  const double* p = PDd + (size_t)row*NPTS;
  for (int i = 0; i < 4; ++i) vals[t + 256*i] = p[t + 256*i];
  __syncthreads();
  for (int k = 0; k < KNN; ++k){
    double bv = -1e300; int bi = NPTS;
    #pragma unroll
    for (int i = 0; i < 4; ++i){
      int id = t + 256*i;
      double v = vals[id];
      if (v > bv || (v == bv && id < bi)){ bv = v; bi = id; }
    }
    rv[t] = bv; ri[t] = bi;
    __syncthreads();
    for (int s = 128; s > 0; s >>= 1){
      if (t < s){
        double v2 = rv[t+s]; int i2 = ri[t+s];
        if (v2 > rv[t] || (v2 == rv[t] && i2 < ri[t])){ rv[t] = v2; ri[t] = i2; }
      }
      __syncthreads();
    }
    if (t == 0){ IDX[(size_t)row*KNN + k] = ri[0]; vals[ri[0]] = -1e300; }
    __syncthreads();
  }
}

// ---------------- OUT[b,m,n] = sum_c A[m,c] * X[b,c,n] (fp32) ----------------
// split==0: A[m,c] = W[m*lda+c]   (plain, M rows)
// split==1: rows [0,O): w1 ; rows [O,2O): w2-w1  (edge-conv v/u projections)
__global__ void lin_gemm(const float* __restrict__ W, int M, int Cdim, int lda, int split, int O,
                         const float* __restrict__ X, long bstride, int coff,
                         float* __restrict__ OUT){
  __shared__ float As[16][65];
  __shared__ float Bs[16][64];
  int b = blockIdx.z;
  int m0 = blockIdx.y * 64;
  int n0 = blockIdx.x * 64;
  int t = threadIdx.x;
  const float* Xb = X + (size_t)b*bstride + (size_t)coff*NPTS;
  float acc[4][4] = {};
  int akk = t & 15;
  int amm = t >> 4;
  int lr = t >> 4;
  int lc = (t & 15) << 2;
  for (int k0 = 0; k0 < Cdim; k0 += 16){
    #pragma unroll
    for (int i = 0; i < 4; ++i){
      int mm = amm + i*16;
      int m = m0 + mm;
      int c = k0 + akk;
      float aval = 0.f;
      if (c < Cdim){
        if (!split)      aval = W[(size_t)m*lda + c];
        else if (m < O)  aval = W[(size_t)m*lda + c];
        else             aval = W[(size_t)(m-O)*lda + Cdim + c] - W[(size_t)(m-O)*lda + c];
      }
      As[akk][mm] = aval;
    }
    float4 bv = make_float4(0,0,0,0);
    if (k0 + lr < Cdim)
      bv = *(const float4*)(Xb + (size_t)(k0+lr)*NPTS + n0 + lc);
    *(float4*)&Bs[lr][lc] = bv;
    __syncthreads();
    int tr = (t >> 4) << 2;
    int tc = (t & 15) << 2;
    #pragma unroll
    for (int kk = 0; kk < 16; ++kk){
      float a0 = As[kk][tr+0], a1 = As[kk][tr+1], a2 = As[kk][tr+2], a3 = As[kk][tr+3];
      float b0 = Bs[kk][tc+0], b1 = Bs[kk][tc+1], b2 = Bs[kk][tc+2], b3 = Bs[kk][tc+3];
      acc[0][0] += a0*b0; acc[0][1] += a0*b1; acc[0][2] += a0*b2; acc[0][3] += a0*b3;
      acc[1][0] += a1*b0; acc[1][1] += a1*b1; acc[1][2] += a1*b2; acc[1][3] += a1*b3;
      acc[2][0] += a2*b0; acc[2][1] += a2*b1; acc[2][2] += a2*b2; acc[2][3] += a2*b3;
      acc[3][0] += a3*b0; acc[3][1] += a3*b1; acc[3][2] += a3*b2; acc[3][3] += a3*b3;
    }
    __syncthreads();
  }
  int tr = (t >> 4) << 2;
  int tc = (t & 15) << 2;
  #pragma unroll
  for (int i = 0; i < 4; ++i){
    int m = m0 + tr + i;
    *(float4*)(OUT + ((size_t)b*M + m)*NPTS + n0 + tc) =
        make_float4(acc[i][0], acc[i][1], acc[i][2], acc[i][3]);
  }
}

// ---------------- per (b,o): ymax/ymin over k of (u[n] + v[idx[n,k]]) + BN partial sums --------
__global__ void edge_stats(const float* __restrict__ V, const int* __restrict__ IDX, int O,
                           float* __restrict__ YMX, float* __restrict__ YMN,
                           float* __restrict__ S1P, float* __restrict__ S2P){
  __shared__ float vrow[NPTS];
  __shared__ float urow[NPTS];
  __shared__ float r1[256];
  __shared__ float r2[256];
  int b = blockIdx.x / O;
  int o = blockIdx.x % O;
  int t = threadIdx.x;
  const float* vp = V + ((size_t)b*2*O + o)*NPTS;
  const float* up = V + ((size_t)b*2*O + O + o)*NPTS;
  for (int i = 0; i < 4; ++i){ vrow[t+256*i] = vp[t+256*i]; urow[t+256*i] = up[t+256*i]; }
  __syncthreads();
  float s1 = 0.f, s2 = 0.f;
  size_t obase = ((size_t)b*O + o)*NPTS;
  for (int i = 0; i < 4; ++i){
    int n = t + 256*i;
    float un = urow[n];
    const int* ip = IDX + ((size_t)b*NPTS + n)*KNN;
    float mx = -1e38f, mn = 1e38f;
    #pragma unroll
    for (int k = 0; k < KNN; ++k){
      float val = un + vrow[ip[k]];
      mx = fmaxf(mx, val); mn = fminf(mn, val);
      s1 += val; s2 += val*val;
    }
    YMX[obase + n] = mx;
    YMN[obase + n] = mn;
  }
  r1[t] = s1; r2[t] = s2;
  __syncthreads();
  for (int s = 128; s > 0; s >>= 1){
    if (t < s){ r1[t] += r1[t+s]; r2[t] += r2[t+s]; }
    __syncthreads();
  }
  if (t == 0){ S1P[b*O + o] = r1[0]; S2P[b*O + o] = r2[0]; }
}

// ---------------- BN finalize: scale/shift per channel ----------------
__global__ void bn_finalize(const float* __restrict__ S1P, const float* __restrict__ S2P,
                            int O, int nparts, float cnt,
                            const float* __restrict__ gw, const float* __restrict__ gb,
                            float* __restrict__ scale, float* __restrict__ shift){
  int o = blockIdx.x*blockDim.x + threadIdx.x;
  if (o >= O) return;
  float s1 = 0.f, s2 = 0.f;
  for (int i = 0; i < nparts; ++i){ s1 += S1P[i*O + o]; s2 += S2P[i*O + o]; }
  float mean = s1 / cnt;
  float var = s2 / cnt - mean*mean;
  var = fmaxf(var, 0.f);
  float sc = gw[o] * rsqrtf(var + EPSBN);
  scale[o] = sc;
  shift[o] = gb[o] - mean*sc;
}

// ---------------- apply BN+lrelu to max-over-k, write into CAT slice ----------------
__global__ void edge_apply(const float* __restrict__ YMX, const float* __restrict__ YMN,
                           const float* __restrict__ scale, const float* __restrict__ shift,
                           int O, float* __restrict__ CAT, int coff_out){
  int g = blockIdx.x*blockDim.x + threadIdx.x;
  int n = g & (NPTS-1);
  int o = (g >> 10) % O;
  int b = (g >> 10) / O;
  float s = scale[o];
  float v = (s >= 0.f) ? YMX[g] : YMN[g];
  float r = s*v + shift[o];
  CAT[((size_t)b*512 + coff_out + o)*NPTS + n] = lrelu_f(r);
}

// ---------------- conv5 BN stats ----------------
__global__ void y5_stats(const float* __restrict__ Y5, float* __restrict__ S1, float* __restrict__ S2){
  __shared__ float r1[256], r2[256];
  int o = blockIdx.x;
  int t = threadIdx.x;
  float s1 = 0.f, s2 = 0.f;
  for (int b = 0; b < NBATCH; ++b){
    const float* p = Y5 + ((size_t)b*1024 + o)*NPTS;
    for (int n = t; n < NPTS; n += 256){ float v = p[n]; s1 += v; s2 += v*v; }
  }
  r1[t] = s1; r2[t] = s2;
  __syncthreads();
  for (int s = 128; s > 0; s >>= 1){
    if (t < s){ r1[t] += r1[t+s]; r2[t] += r2[t+s]; }
    __syncthreads();
  }
  if (t == 0){ S1[o] = r1[0]; S2[o] = r2[0]; }
}

// ---------------- head: feat = [max_n, mean_n] of lrelu(BN(y5)) ----------------
__global__ void head_kernel(const float* __restrict__ Y5, const float* __restrict__ scale,
                            const float* __restrict__ shift, float* __restrict__ FEAT){
  __shared__ float rm[256], rs[256];
  int o = blockIdx.x & 1023;
  int b = blockIdx.x >> 10;
  int t = threadIdx.x;
  float s = scale[o], sh = shift[o];
  const float* p = Y5 + ((size_t)b*1024 + o)*NPTS;
  float mx = -1e38f, sm = 0.f;
  for (int n = t; n < NPTS; n += 256){
    float v = lrelu_f(s*p[n] + sh);
    mx = fmaxf(mx, v); sm += v;
  }
  rm[t] = mx; rs[t] = sm;
  __syncthreads();
  for (int st = 128; st > 0; st >>= 1){
    if (t < st){ rm[t] = fmaxf(rm[t], rm[t+st]); rs[t] += rs[t+st]; }
    __syncthreads();
  }
  if (t == 0){
    FEAT[(size_t)b*2048 + o]        = rm[0];
    FEAT[(size_t)b*2048 + 1024 + o] = rs[0] * (1.f/NPTS);
  }
}

// ---------------- FC + batch-BN(8) + lrelu ----------------
__global__ void fc_bn(const float* __restrict__ IN, int ID, int OD,
                      const float* __restrict__ W, const float* __restrict__ bias,
                      const float* __restrict__ gw, const float* __restrict__ gb,
                      float* __restrict__ OUT){
  __shared__ float red[256][8];
  int f = blockIdx.x;
  int t = threadIdx.x;
  float acc[8] = {};
  const float* wr = W + (size_t)f*ID;
  for (int j = t; j < ID; j += 256){
    float wv = wr[j];
    #pragma unroll
    for (int b = 0; b < 8; ++b) acc[b] += IN[b*ID + j] * wv;
  }
  #pragma unroll
  for (int b = 0; b < 8; ++b) red[t][b] = acc[b];
  __syncthreads();
  for (int s = 128; s > 0; s >>= 1){
    if (t < s){
      #pragma unroll
      for (int b = 0; b < 8; ++b) red[t][b] += red[t+s][b];
    }
    __syncthreads();
  }
  if (t == 0){
    float h[8], mean = 0.f;
    #pragma unroll
    for (int b = 0; b < 8; ++b){ h[b] = red[0][b] + bias[f]; mean += h[b]; }
    mean *= 0.125f;
    float var = 0.f;
    #pragma unroll
    for (int b = 0; b < 8; ++b){ float d = h[b]-mean; var += d*d; }
    var *= 0.125f;
    float sc = gw[f]*rsqrtf(var + EPSBN);
    float sh = gb[f] - mean*sc;
    #pragma unroll
    for (int b = 0; b < 8; ++b) OUT[b*OD + f] = lrelu_f(sc*h[b] + sh);
  }
}

// ---------------- final linear (no BN) ----------------
__global__ void fc_out(const float* __restrict__ IN, const float* __restrict__ W,
                       const float* __restrict__ bias, float* __restrict__ OUT){
  __shared__ float red[256][8];
  int j = blockIdx.x;
  int t = threadIdx.x;
  float wv = W[(size_t)j*256 + t];
  #pragma unroll
  for (int b = 0; b < 8; ++b) red[t][b] = IN[b*256 + t] * wv;
  __syncthreads();
  for (int s = 128; s > 0; s >>= 1){
    if (t < s){
      #pragma unroll
      for (int b = 0; b < 8; ++b) red[t][b] += red[t+s][b];
    }
    __syncthreads();
  }
  if (t == 0){
    #pragma unroll
    for (int b = 0; b < 8; ++b) OUT[b*40 + j] = red[0][b] + bias[j];
  }
}

extern "C" void kernel_launch(void* const* d_in, const int* in_sizes, int n_in,
                              void* d_out, int out_size, void* d_ws, size_t ws_size,
                              hipStream_t stream) {
  const float* x   = (const float*)d_in[0];
  const float* cw[5] = { (const float*)d_in[1], (const float*)d_in[2], (const float*)d_in[3],
                         (const float*)d_in[4], (const float*)d_in[5] };
  const float* bw[7]; const float* bbv[7];
  for (int i = 0; i < 7; ++i){ bw[i] = (const float*)d_in[6+2*i]; bbv[i] = (const float*)d_in[7+2*i]; }
  const float* l1w = (const float*)d_in[20]; const float* l1b = (const float*)d_in[21];
  const float* l2w = (const float*)d_in[22]; const float* l2b = (const float*)d_in[23];
  const float* l3w = (const float*)d_in[24]; const float* l3b = (const float*)d_in[25];
  float* out = (float*)d_out;

  float* ws = (float*)d_ws;
  // Region A (16M floats = 64MB), time-multiplexed:
  //   phase 1 (per edge layer): PDd = 8M doubles (pd matrix, dead after topk)
  //   phase 2 (per edge layer): V (4M), YMX (2M @ +4M), YMN (2M @ +6M)
  //   phase 3 (conv5): Y5 = 8M floats
  double* PDd  = (double*)ws;             // 8M doubles
  float* V     = ws;                      // 4M floats
  float* YMX   = ws + 4194304;            // 2M
  float* YMN   = ws + 6291456;            // 2M
  float* Y5    = ws;                      // 8M
  float* CAT   = ws + 16777216;           // 4M  (B,512,N)
  double* XXd  = (double*)(ws + 20971520);// 8192 doubles (16384 float slots)
  int*   IDX   = (int*)(ws + 20987904);   // 163840 ints
  float* S1P   = ws + 21151744;           // 8192
  float* S2P   = ws + 21159936;           // 8192
  float* SCALE = ws + 21168128;           // 1024
  float* SHIFT = ws + 21169152;           // 1024
  float* FEAT  = ws + 21170176;           // 16384
  float* H1    = ws + 21186560;           // 4096
  float* H2    = ws + 21190656;           // 2048

  // edge layers: {Cin, O, input ptr, bstride, coff_in, weight, bn idx, coff_out}
  struct L { int C, O; const float* in; long bs; int ci; const float* w; int bn; int co; };
  L ls[4] = {
    { 3,   64, x,   (long)3*NPTS,   0,   cw[0], 0, 0   },
    { 64,  64, CAT, (long)512*NPTS, 0,   cw[1], 1, 64  },
    { 64, 128, CAT, (long)512*NPTS, 64,  cw[2], 2, 128 },
    { 128,256, CAT, (long)512*NPTS, 128, cw[3], 3, 256 },
  };

  for (int li = 0; li < 4; ++li){
    L& l = ls[li];
    xx_kernel_f64<<<(NBATCH*NPTS)/256, 256, 0, stream>>>(l.in, l.bs, l.ci, l.C, XXd);
    pd_gemm_f64<<<dim3(16,16,NBATCH), 256, 0, stream>>>(l.in, l.bs, l.ci, l.C, XXd, PDd);
    topk_kernel<<<NBATCH*NPTS, 256, 0, stream>>>(PDd, IDX);
    // PDd dead now; V/YMX/YMN may alias it.
    lin_gemm<<<dim3(16, (2*l.O)/64, NBATCH), 256, 0, stream>>>(
        l.w, 2*l.O, l.C, 2*l.C, 1, l.O, l.in, l.bs, l.ci, V);
    edge_stats<<<NBATCH*l.O, 256, 0, stream>>>(V, IDX, l.O, YMX, YMN, S1P, S2P);
    bn_finalize<<<(l.O+255)/256, 256, 0, stream>>>(
        S1P, S2P, l.O, NBATCH, (float)(NBATCH*NPTS*KNN), bw[l.bn], bbv[l.bn], SCALE, SHIFT);
    edge_apply<<<(NBATCH*l.O*NPTS)/256, 256, 0, stream>>>(YMX, YMN, SCALE, SHIFT, l.O, CAT, l.co);
  }

  // conv5: y5 = c5w (1024x512) @ CAT
  lin_gemm<<<dim3(16,16,NBATCH), 256, 0, stream>>>(
      cw[4], 1024, 512, 512, 0, 0, CAT, (long)512*NPTS, 0, Y5);
  y5_stats<<<1024, 256, 0, stream>>>(Y5, S1P, S2P);
  bn_finalize<<<4, 256, 0, stream>>>(S1P, S2P, 1024, 1, (float)(NBATCH*NPTS),
                                     bw[4], bbv[4], SCALE, SHIFT);
  head_kernel<<<NBATCH*1024, 256, 0, stream>>>(Y5, SCALE, SHIFT, FEAT);

  fc_bn<<<512, 256, 0, stream>>>(FEAT, 2048, 512, l1w, l1b, bw[5], bbv[5], H1);
  fc_bn<<<256, 256, 0, stream>>>(H1, 512, 256, l2w, l2b, bw[6], bbv[6], H2);
  fc_out<<<40, 256, 0, stream>>>(H2, l3w, l3b, out);
}

// Round 3
// 737.594 us; speedup vs baseline: 1.6158x; 1.6158x over previous
//
#include <hip/hip_runtime.h>
#include <math.h>

#define NPTS 1024
#define NBATCH 8
#define KNN 20
#define EPSBN 1e-5f
#define NSLOPE 0.2f

typedef __attribute__((ext_vector_type(8))) short short8_t;
typedef __attribute__((ext_vector_type(4))) float floatx4;

__device__ __forceinline__ float lrelu_f(float x){ return x >= 0.f ? x : NSLOPE*x; }

__device__ __forceinline__ unsigned short f2bf_rne(float f){
  union { float f; unsigned u; } x; x.f = f;
  unsigned r = x.u + 0x7FFFu + ((x.u >> 16) & 1u);
  return (unsigned short)(r >> 16);
}
__device__ __forceinline__ float bf2f(unsigned short h){
  union { float f; unsigned u; } x; x.u = ((unsigned)h) << 16;
  return x.f;
}

// ---------------- xx[b,n] = sum_c X[b,c,n]^2 (f64) ----------------
__global__ void xx_kernel_f64(const float* __restrict__ X, long bstride, int coff, int C,
                              double* __restrict__ XXd){
  int g = blockIdx.x*blockDim.x + threadIdx.x;
  int n = g & (NPTS-1);
  int b = g >> 10;
  const float* p = X + (size_t)b*bstride + (size_t)coff*NPTS + n;
  double s = 0.0;
  for (int c = 0; c < C; ++c){ double v = (double)p[(size_t)c*NPTS]; s += v*v; }
  XXd[g] = s;
}

// ---------------- pd[b,n,m] = 2*dot(x_n,x_m) - xx[n] - xx[m]  (f64 accumulate) ----------------
__global__ void pd_gemm_f64(const float* __restrict__ X, long bstride, int coff, int C,
                            const double* __restrict__ XXd, double* __restrict__ PDd){
  __shared__ double As[16][64];
  __shared__ double Bs[16][64];
  int b = blockIdx.z;
  int r0 = blockIdx.y * 64;
  int q0 = blockIdx.x * 64;
  int t = threadIdx.x;
  int lr = t >> 4;
  int lc = (t & 15) << 2;
  const float* Xb = X + (size_t)b*bstride + (size_t)coff*NPTS;
  const double* xxb = XXd + b*NPTS;
  double acc[4][4] = {};
  for (int k0 = 0; k0 < C; k0 += 16){
    float4 av = make_float4(0,0,0,0);
    float4 bv = make_float4(0,0,0,0);
    if (k0 + lr < C){
      const float* rp = Xb + (size_t)(k0+lr)*NPTS;
      av = *(const float4*)(rp + r0 + lc);
      bv = *(const float4*)(rp + q0 + lc);
    }
    As[lr][lc+0] = (double)av.x; As[lr][lc+1] = (double)av.y;
    As[lr][lc+2] = (double)av.z; As[lr][lc+3] = (double)av.w;
    Bs[lr][lc+0] = (double)bv.x; Bs[lr][lc+1] = (double)bv.y;
    Bs[lr][lc+2] = (double)bv.z; Bs[lr][lc+3] = (double)bv.w;
    __syncthreads();
    int tr = (t >> 4) << 2;
    int tc = (t & 15) << 2;
    #pragma unroll
    for (int kk = 0; kk < 16; ++kk){
      double a0 = As[kk][tr+0], a1 = As[kk][tr+1], a2 = As[kk][tr+2], a3 = As[kk][tr+3];
      double b0 = Bs[kk][tc+0], b1 = Bs[kk][tc+1], b2 = Bs[kk][tc+2], b3 = Bs[kk][tc+3];
      acc[0][0] += a0*b0; acc[0][1] += a0*b1; acc[0][2] += a0*b2; acc[0][3] += a0*b3;
      acc[1][0] += a1*b0; acc[1][1] += a1*b1; acc[1][2] += a1*b2; acc[1][3] += a1*b3;
      acc[2][0] += a2*b0; acc[2][1] += a2*b1; acc[2][2] += a2*b2; acc[2][3] += a2*b3;
      acc[3][0] += a3*b0; acc[3][1] += a3*b1; acc[3][2] += a3*b2; acc[3][3] += a3*b3;
    }
    __syncthreads();
  }
  int tr = (t >> 4) << 2;
  int tc = (t & 15) << 2;
  double x0 = xxb[q0+tc+0], x1 = xxb[q0+tc+1], x2 = xxb[q0+tc+2], x3 = xxb[q0+tc+3];
  #pragma unroll
  for (int i = 0; i < 4; ++i){
    int r = r0 + tr + i;
    double xr = xxb[r];
    double* op = PDd + ((size_t)b*NPTS + r)*NPTS + q0 + tc;
    op[0] = 2.0*acc[i][0] - xr - x0;
    op[1] = 2.0*acc[i][1] - xr - x1;
    op[2] = 2.0*acc[i][2] - xr - x2;
    op[3] = 2.0*acc[i][3] - xr - x3;
  }
}

// ---------------- top-20: one wave per row, values in registers ----------------
__global__ __launch_bounds__(256) void topk_wave(const double* __restrict__ PDd,
                                                 int* __restrict__ IDX){
  int wid = threadIdx.x >> 6;
  int lane = threadIdx.x & 63;
  int row = blockIdx.x*4 + wid;           // b*NPTS + n
  const double* p = PDd + (size_t)row*NPTS;
  double v[16];
  #pragma unroll
  for (int j = 0; j < 16; ++j) v[j] = p[j*64 + lane];
  for (int k = 0; k < KNN; ++k){
    // local argmax (strict > keeps lowest j => lowest global index)
    double bv = v[0]; int bj = 0;
    #pragma unroll
    for (int j = 1; j < 16; ++j){ if (v[j] > bv){ bv = v[j]; bj = j; } }
    int bi = bj*64 + lane;
    // 64-lane butterfly: value desc, index asc on tie
    #pragma unroll
    for (int m = 1; m < 64; m <<= 1){
      double ov = __shfl_xor(bv, m, 64);
      int    oi = __shfl_xor(bi, m, 64);
      if (ov > bv || (ov == bv && oi < bi)){ bv = ov; bi = oi; }
    }
    if (lane == 0) IDX[(size_t)row*KNN + k] = bi;
    // remove winner
    int wl = bi & 63, wj = bi >> 6;
    #pragma unroll
    for (int j = 0; j < 16; ++j)
      if (lane == wl && j == wj) v[j] = -1e300;
  }
}

// ---------------- OUT[b,m,n] = sum_c A[m,c] * X[b,c,n] (fp32, edge layers) ----------------
__global__ void lin_gemm(const float* __restrict__ W, int M, int Cdim, int lda, int split, int O,
                         const float* __restrict__ X, long bstride, int coff,
                         float* __restrict__ OUT){
  __shared__ float As[16][65];
  __shared__ float Bs[16][64];
  int b = blockIdx.z;
  int m0 = blockIdx.y * 64;
  int n0 = blockIdx.x * 64;
  int t = threadIdx.x;
  const float* Xb = X + (size_t)b*bstride + (size_t)coff*NPTS;
  float acc[4][4] = {};
  int akk = t & 15;
  int amm = t >> 4;
  int lr = t >> 4;
  int lc = (t & 15) << 2;
  for (int k0 = 0; k0 < Cdim; k0 += 16){
    #pragma unroll
    for (int i = 0; i < 4; ++i){
      int mm = amm + i*16;
      int m = m0 + mm;
      int c = k0 + akk;
      float aval = 0.f;
      if (c < Cdim){
        if (!split)      aval = W[(size_t)m*lda + c];
        else if (m < O)  aval = W[(size_t)m*lda + c];
        else             aval = W[(size_t)(m-O)*lda + Cdim + c] - W[(size_t)(m-O)*lda + c];
      }
      As[akk][mm] = aval;
    }
    float4 bv = make_float4(0,0,0,0);
    if (k0 + lr < Cdim)
      bv = *(const float4*)(Xb + (size_t)(k0+lr)*NPTS + n0 + lc);
    *(float4*)&Bs[lr][lc] = bv;
    __syncthreads();
    int tr = (t >> 4) << 2;
    int tc = (t & 15) << 2;
    #pragma unroll
    for (int kk = 0; kk < 16; ++kk){
      float a0 = As[kk][tr+0], a1 = As[kk][tr+1], a2 = As[kk][tr+2], a3 = As[kk][tr+3];
      float b0 = Bs[kk][tc+0], b1 = Bs[kk][tc+1], b2 = Bs[kk][tc+2], b3 = Bs[kk][tc+3];
      acc[0][0] += a0*b0; acc[0][1] += a0*b1; acc[0][2] += a0*b2; acc[0][3] += a0*b3;
      acc[1][0] += a1*b0; acc[1][1] += a1*b1; acc[1][2] += a1*b2; acc[1][3] += a1*b3;
      acc[2][0] += a2*b0; acc[2][1] += a2*b1; acc[2][2] += a2*b2; acc[2][3] += a2*b3;
      acc[3][0] += a3*b0; acc[3][1] += a3*b1; acc[3][2] += a3*b2; acc[3][3] += a3*b3;
    }
    __syncthreads();
  }
  int tr = (t >> 4) << 2;
  int tc = (t & 15) << 2;
  #pragma unroll
  for (int i = 0; i < 4; ++i){
    int m = m0 + tr + i;
    *(float4*)(OUT + ((size_t)b*M + m)*NPTS + n0 + tc) =
        make_float4(acc[i][0], acc[i][1], acc[i][2], acc[i][3]);
  }
}

// ---------------- per (b,o): ymax/ymin over k of (u[n] + v[idx[n,k]]) + BN partial sums --------
__global__ void edge_stats(const float* __restrict__ V, const int* __restrict__ IDX, int O,
                           float* __restrict__ YMX, float* __restrict__ YMN,
                           float* __restrict__ S1P, float* __restrict__ S2P){
  __shared__ float vrow[NPTS];
  __shared__ float urow[NPTS];
  __shared__ float r1[256];
  __shared__ float r2[256];
  int b = blockIdx.x / O;
  int o = blockIdx.x % O;
  int t = threadIdx.x;
  const float* vp = V + ((size_t)b*2*O + o)*NPTS;
  const float* up = V + ((size_t)b*2*O + O + o)*NPTS;
  for (int i = 0; i < 4; ++i){ vrow[t+256*i] = vp[t+256*i]; urow[t+256*i] = up[t+256*i]; }
  __syncthreads();
  float s1 = 0.f, s2 = 0.f;
  size_t obase = ((size_t)b*O + o)*NPTS;
  for (int i = 0; i < 4; ++i){
    int n = t + 256*i;
    float un = urow[n];
    const int* ip = IDX + ((size_t)b*NPTS + n)*KNN;
    float mx = -1e38f, mn = 1e38f;
    #pragma unroll
    for (int k = 0; k < KNN; ++k){
      float val = un + vrow[ip[k]];
      mx = fmaxf(mx, val); mn = fminf(mn, val);
      s1 += val; s2 += val*val;
    }
    YMX[obase + n] = mx;
    YMN[obase + n] = mn;
  }
  r1[t] = s1; r2[t] = s2;
  __syncthreads();
  for (int s = 128; s > 0; s >>= 1){
    if (t < s){ r1[t] += r1[t+s]; r2[t] += r2[t+s]; }
    __syncthreads();
  }
  if (t == 0){ S1P[b*O + o] = r1[0]; S2P[b*O + o] = r2[0]; }
}

// ---------------- BN finalize ----------------
__global__ void bn_finalize(const float* __restrict__ S1P, const float* __restrict__ S2P,
                            int O, int nparts, float cnt,
                            const float* __restrict__ gw, const float* __restrict__ gb,
                            float* __restrict__ scale, float* __restrict__ shift){
  int o = blockIdx.x*blockDim.x + threadIdx.x;
  if (o >= O) return;
  float s1 = 0.f, s2 = 0.f;
  for (int i = 0; i < nparts; ++i){ s1 += S1P[i*O + o]; s2 += S2P[i*O + o]; }
  float mean = s1 / cnt;
  float var = s2 / cnt - mean*mean;
  var = fmaxf(var, 0.f);
  float sc = gw[o] * rsqrtf(var + EPSBN);
  scale[o] = sc;
  shift[o] = gb[o] - mean*sc;
}

// ---------------- apply BN+lrelu to max-over-k, write into CAT slice ----------------
__global__ void edge_apply(const float* __restrict__ YMX, const float* __restrict__ YMN,
                           const float* __restrict__ scale, const float* __restrict__ shift,
                           int O, float* __restrict__ CAT, int coff_out){
  int g = blockIdx.x*blockDim.x + threadIdx.x;
  int n = g & (NPTS-1);
  int o = (g >> 10) % O;
  int b = (g >> 10) / O;
  float s = scale[o];
  float v = (s >= 0.f) ? YMX[g] : YMN[g];
  float r = s*v + shift[o];
  CAT[((size_t)b*512 + coff_out + o)*NPTS + n] = lrelu_f(r);
}

// ---------------- W -> bf16 hi/lo split ----------------
__global__ void wsplit(const float* __restrict__ W, int nelem,
                       unsigned short* __restrict__ Wh, unsigned short* __restrict__ Wl){
  int i = blockIdx.x*blockDim.x + threadIdx.x;
  if (i >= nelem) return;
  float f = W[i];
  unsigned short hi = f2bf_rne(f);
  Wh[i] = hi;
  Wl[i] = f2bf_rne(f - bf2f(hi));
}

// ---------------- CAT (b,c,n) -> CATt (b,n,c) bf16 hi/lo, LDS tile transpose ----------------
__global__ void catsplit_t(const float* __restrict__ CAT,
                           unsigned short* __restrict__ Th, unsigned short* __restrict__ Tl){
  __shared__ float tile[32][33];
  int b = blockIdx.z;
  int c0 = blockIdx.y * 32;
  int n0 = blockIdx.x * 32;
  int t = threadIdx.x;
  int r = t >> 3, q = t & 7;
  float4 rv = *(const float4*)(CAT + ((size_t)b*512 + c0 + r)*NPTS + n0 + q*4);
  tile[r][q*4+0] = rv.x; tile[r][q*4+1] = rv.y; tile[r][q*4+2] = rv.z; tile[r][q*4+3] = rv.w;
  __syncthreads();
  // write: row = n, contiguous in c
  ushort4 oh, ol;
  float f0 = tile[q*4+0][r], f1 = tile[q*4+1][r], f2 = tile[q*4+2][r], f3 = tile[q*4+3][r];
  oh.x = f2bf_rne(f0); ol.x = f2bf_rne(f0 - bf2f(oh.x));
  oh.y = f2bf_rne(f1); ol.y = f2bf_rne(f1 - bf2f(oh.y));
  oh.z = f2bf_rne(f2); ol.z = f2bf_rne(f2 - bf2f(oh.z));
  oh.w = f2bf_rne(f3); ol.w = f2bf_rne(f3 - bf2f(oh.w));
  size_t ob = ((size_t)b*NPTS + n0 + r)*512 + c0 + q*4;
  *(ushort4*)(Th + ob) = oh;
  *(ushort4*)(Tl + ob) = ol;
}

// ---------------- conv5: Y5[b,m,n] = sum_c W[m,c]*CAT[b,c,n] via bf16x3 MFMA ----------------
// A operand = CATt (i=n, k=c), B operand = W (j=m, k=c). D[row=n][col=m].
#define LROW 40   // padded LDS row (ushorts) to break bank conflicts
__global__ __launch_bounds__(256) void conv5_mfma(
    const unsigned short* __restrict__ Ath, const unsigned short* __restrict__ Atl,
    const unsigned short* __restrict__ Wh,  const unsigned short* __restrict__ Wl,
    float* __restrict__ OUT){
  __shared__ __align__(16) unsigned short Ah[128*LROW];
  __shared__ __align__(16) unsigned short Al[128*LROW];
  __shared__ __align__(16) unsigned short Bh[128*LROW];
  __shared__ __align__(16) unsigned short Bl[128*LROW];
  int b  = blockIdx.z;
  int n0 = blockIdx.x * 128;
  int m0 = blockIdx.y * 128;
  int t = threadIdx.x;
  int lane = t & 63, wid = t >> 6;
  int wn = (wid & 1) * 64;   // wave's n offset in block tile
  int wm = (wid >> 1) * 64;  // wave's m offset
  int fr = lane & 15;
  int fq = (lane >> 4) * 8;
  floatx4 acc[4][4];
  #pragma unroll
  for (int i = 0; i < 4; ++i)
    #pragma unroll
    for (int j = 0; j < 4; ++j) acc[i][j] = (floatx4)(0.f);

  for (int k0 = 0; k0 < 512; k0 += 32){
    // stage 4 tiles of 128x32 ushort
    #pragma unroll
    for (int c = 0; c < 2; ++c){
      int ch = t + 256*c;              // 0..511
      int row = ch >> 2, part = (ch & 3)*8;
      size_t ga = ((size_t)b*NPTS + n0 + row)*512 + k0 + part;
      size_t gb = ((size_t)(m0 + row))*512 + k0 + part;
      *(short8_t*)&Ah[row*LROW + part] = *(const short8_t*)&Ath[ga];
      *(short8_t*)&Al[row*LROW + part] = *(const short8_t*)&Atl[ga];
      *(short8_t*)&Bh[row*LROW + part] = *(const short8_t*)&Wh[gb];
      *(short8_t*)&Bl[row*LROW + part] = *(const short8_t*)&Wl[gb];
    }
    __syncthreads();
    short8_t afh[4], afl[4], bfh[4], bfl[4];
    #pragma unroll
    for (int ni = 0; ni < 4; ++ni){
      int r = (wn + ni*16 + fr)*LROW + fq;
      afh[ni] = *(const short8_t*)&Ah[r];
      afl[ni] = *(const short8_t*)&Al[r];
    }
    #pragma unroll
    for (int mi = 0; mi < 4; ++mi){
      int r = (wm + mi*16 + fr)*LROW + fq;
      bfh[mi] = *(const short8_t*)&Bh[r];
      bfl[mi] = *(const short8_t*)&Bl[r];
    }
    #pragma unroll
    for (int ni = 0; ni < 4; ++ni)
      #pragma unroll
      for (int mi = 0; mi < 4; ++mi){
        acc[ni][mi] = __builtin_amdgcn_mfma_f32_16x16x32_bf16(afh[ni], bfh[mi], acc[ni][mi], 0, 0, 0);
        acc[ni][mi] = __builtin_amdgcn_mfma_f32_16x16x32_bf16(afl[ni], bfh[mi], acc[ni][mi], 0, 0, 0);
        acc[ni][mi] = __builtin_amdgcn_mfma_f32_16x16x32_bf16(afh[ni], bfl[mi], acc[ni][mi], 0, 0, 0);
      }
    __syncthreads();
  }
  // D layout: row(n) = quad*4 + reg, col(m) = lane&15
  int col = lane & 15;
  int rquad = (lane >> 4) * 4;
  #pragma unroll
  for (int ni = 0; ni < 4; ++ni)
    #pragma unroll
    for (int mi = 0; mi < 4; ++mi){
      int m = m0 + wm + mi*16 + col;
      int n = n0 + wn + ni*16 + rquad;
      *(floatx4*)(OUT + ((size_t)b*1024 + m)*NPTS + n) = acc[ni][mi];
    }
}

// ---------------- conv5 BN stats ----------------
__global__ void y5_stats(const float* __restrict__ Y5, float* __restrict__ S1, float* __restrict__ S2){
  __shared__ float r1[256], r2[256];
  int o = blockIdx.x;
  int t = threadIdx.x;
  float s1 = 0.f, s2 = 0.f;
  for (int b = 0; b < NBATCH; ++b){
    const float* p = Y5 + ((size_t)b*1024 + o)*NPTS;
    for (int n = t; n < NPTS; n += 256){ float v = p[n]; s1 += v; s2 += v*v; }
  }
  r1[t] = s1; r2[t] = s2;
  __syncthreads();
  for (int s = 128; s > 0; s >>= 1){
    if (t < s){ r1[t] += r1[t+s]; r2[t] += r2[t+s]; }
    __syncthreads();
  }
  if (t == 0){ S1[o] = r1[0]; S2[o] = r2[0]; }
}

// ---------------- head: feat = [max_n, mean_n] of lrelu(BN(y5)) ----------------
__global__ void head_kernel(const float* __restrict__ Y5, const float* __restrict__ scale,
                            const float* __restrict__ shift, float* __restrict__ FEAT){
  __shared__ float rm[256], rs[256];
  int o = blockIdx.x & 1023;
  int b = blockIdx.x >> 10;
  int t = threadIdx.x;
  float s = scale[o], sh = shift[o];
  const float* p = Y5 + ((size_t)b*1024 + o)*NPTS;
  float mx = -1e38f, sm = 0.f;
  for (int n = t; n < NPTS; n += 256){
    float v = lrelu_f(s*p[n] + sh);
    mx = fmaxf(mx, v); sm += v;
  }
  rm[t] = mx; rs[t] = sm;
  __syncthreads();
  for (int st = 128; st > 0; st >>= 1){
    if (t < st){ rm[t] = fmaxf(rm[t], rm[t+st]); rs[t] += rs[t+st]; }
    __syncthreads();
  }
  if (t == 0){
    FEAT[(size_t)b*2048 + o]        = rm[0];
    FEAT[(size_t)b*2048 + 1024 + o] = rs[0] * (1.f/NPTS);
  }
}

// ---------------- FC + batch-BN(8) + lrelu ----------------
__global__ void fc_bn(const float* __restrict__ IN, int ID, int OD,
                      const float* __restrict__ W, const float* __restrict__ bias,
                      const float* __restrict__ gw, const float* __restrict__ gb,
                      float* __restrict__ OUT){
  __shared__ float red[256][8];
  int f = blockIdx.x;
  int t = threadIdx.x;
  float acc[8] = {};
  const float* wr = W + (size_t)f*ID;
  for (int j = t; j < ID; j += 256){
    float wv = wr[j];
    #pragma unroll
    for (int b = 0; b < 8; ++b) acc[b] += IN[b*ID + j] * wv;
  }
  #pragma unroll
  for (int b = 0; b < 8; ++b) red[t][b] = acc[b];
  __syncthreads();
  for (int s = 128; s > 0; s >>= 1){
    if (t < s){
      #pragma unroll
      for (int b = 0; b < 8; ++b) red[t][b] += red[t+s][b];
    }
    __syncthreads();
  }
  if (t == 0){
    float h[8], mean = 0.f;
    #pragma unroll
    for (int b = 0; b < 8; ++b){ h[b] = red[0][b] + bias[f]; mean += h[b]; }
    mean *= 0.125f;
    float var = 0.f;
    #pragma unroll
    for (int b = 0; b < 8; ++b){ float d = h[b]-mean; var += d*d; }
    var *= 0.125f;
    float sc = gw[f]*rsqrtf(var + EPSBN);
    float sh = gb[f] - mean*sc;
    #pragma unroll
    for (int b = 0; b < 8; ++b) OUT[b*OD + f] = lrelu_f(sc*h[b] + sh);
  }
}

// ---------------- final linear (no BN) ----------------
__global__ void fc_out(const float* __restrict__ IN, const float* __restrict__ W,
                       const float* __restrict__ bias, float* __restrict__ OUT){
  __shared__ float red[256][8];
  int j = blockIdx.x;
  int t = threadIdx.x;
  float wv = W[(size_t)j*256 + t];
  #pragma unroll
  for (int b = 0; b < 8; ++b) red[t][b] = IN[b*256 + t] * wv;
  __syncthreads();
  for (int s = 128; s > 0; s >>= 1){
    if (t < s){
      #pragma unroll
      for (int b = 0; b < 8; ++b) red[t][b] += red[t+s][b];
    }
    __syncthreads();
  }
  if (t == 0){
    #pragma unroll
    for (int b = 0; b < 8; ++b) OUT[b*40 + j] = red[0][b] + bias[j];
  }
}

extern "C" void kernel_launch(void* const* d_in, const int* in_sizes, int n_in,
                              void* d_out, int out_size, void* d_ws, size_t ws_size,
                              hipStream_t stream) {
  const float* x   = (const float*)d_in[0];
  const float* cw[5] = { (const float*)d_in[1], (const float*)d_in[2], (const float*)d_in[3],
                         (const float*)d_in[4], (const float*)d_in[5] };
  const float* bw[7]; const float* bbv[7];
  for (int i = 0; i < 7; ++i){ bw[i] = (const float*)d_in[6+2*i]; bbv[i] = (const float*)d_in[7+2*i]; }
  const float* l1w = (const float*)d_in[20]; const float* l1b = (const float*)d_in[21];
  const float* l2w = (const float*)d_in[22]; const float* l2b = (const float*)d_in[23];
  const float* l3w = (const float*)d_in[24]; const float* l3b = (const float*)d_in[25];
  float* out = (float*)d_out;

  float* ws = (float*)d_ws;
  // Region A (slots 0..16777215, 64MB), time-multiplexed:
  //   per edge layer: PDd (8M doubles) -> then V(4M f32)/YMX/YMN
  //   conv5 phase: Y5 (8M f32) at 0; bf16 conversions at slots 8388608..13107200
  double* PDd  = (double*)ws;
  float* V     = ws;
  float* YMX   = ws + 4194304;
  float* YMN   = ws + 6291456;
  float* Y5    = ws;
  unsigned short* CATth = (unsigned short*)(ws + 8388608);   // 4M ushort (8MB)
  unsigned short* CATtl = (unsigned short*)(ws + 10485760);  // 4M ushort
  unsigned short* WhP   = (unsigned short*)(ws + 12582912);  // 512K ushort
  unsigned short* WlP   = (unsigned short*)(ws + 12845056);  // 512K ushort
  float* CAT   = ws + 16777216;           // 4M  (B,512,N)
  double* XXd  = (double*)(ws + 20971520);// 8192 doubles
  int*   IDX   = (int*)(ws + 20987904);   // 163840 ints
  float* S1P   = ws + 21151744;
  float* S2P   = ws + 21159936;
  float* SCALE = ws + 21168128;
  float* SHIFT = ws + 21169152;
  float* FEAT  = ws + 21170176;
  float* H1    = ws + 21186560;
  float* H2    = ws + 21190656;

  struct L { int C, O; const float* in; long bs; int ci; const float* w; int bn; int co; };
  L ls[4] = {
    { 3,   64, x,   (long)3*NPTS,   0,   cw[0], 0, 0   },
    { 64,  64, CAT, (long)512*NPTS, 0,   cw[1], 1, 64  },
    { 64, 128, CAT, (long)512*NPTS, 64,  cw[2], 2, 128 },
    { 128,256, CAT, (long)512*NPTS, 128, cw[3], 3, 256 },
  };

  for (int li = 0; li < 4; ++li){
    L& l = ls[li];
    xx_kernel_f64<<<(NBATCH*NPTS)/256, 256, 0, stream>>>(l.in, l.bs, l.ci, l.C, XXd);
    pd_gemm_f64<<<dim3(16,16,NBATCH), 256, 0, stream>>>(l.in, l.bs, l.ci, l.C, XXd, PDd);
    topk_wave<<<(NBATCH*NPTS)/4, 256, 0, stream>>>(PDd, IDX);
    lin_gemm<<<dim3(16, (2*l.O)/64, NBATCH), 256, 0, stream>>>(
        l.w, 2*l.O, l.C, 2*l.C, 1, l.O, l.in, l.bs, l.ci, V);
    edge_stats<<<NBATCH*l.O, 256, 0, stream>>>(V, IDX, l.O, YMX, YMN, S1P, S2P);
    bn_finalize<<<(l.O+255)/256, 256, 0, stream>>>(
        S1P, S2P, l.O, NBATCH, (float)(NBATCH*NPTS*KNN), bw[l.bn], bbv[l.bn], SCALE, SHIFT);
    edge_apply<<<(NBATCH*l.O*NPTS)/256, 256, 0, stream>>>(YMX, YMN, SCALE, SHIFT, l.O, CAT, l.co);
  }

  // conv5 via bf16x3 MFMA
  wsplit<<<(1024*512+255)/256, 256, 0, stream>>>(cw[4], 1024*512, WhP, WlP);
  catsplit_t<<<dim3(32,16,NBATCH), 256, 0, stream>>>(CAT, CATth, CATtl);
  conv5_mfma<<<dim3(8,8,NBATCH), 256, 0, stream>>>(CATth, CATtl, WhP, WlP, Y5);

  y5_stats<<<1024, 256, 0, stream>>>(Y5, S1P, S2P);
  bn_finalize<<<4, 256, 0, stream>>>(S1P, S2P, 1024, 1, (float)(NBATCH*NPTS),
                                     bw[4], bbv[4], SCALE, SHIFT);
  head_kernel<<<NBATCH*1024, 256, 0, stream>>>(Y5, SCALE, SHIFT, FEAT);

  fc_bn<<<512, 256, 0, stream>>>(FEAT, 2048, 512, l1w, l1b, bw[5], bbv[5], H1);
  fc_bn<<<256, 256, 0, stream>>>(H1, 512, 256, l2w, l2b, bw[6], bbv[6], H2);
  fc_out<<<40, 256, 0, stream>>>(H2, l3w, l3b, out);
}